// Round 11
// baseline (1398.073 us; speedup 1.0000x reference)
//
#include <hip/hip_runtime.h>
#include <math.h>

namespace {

constexpr int Bb = 4, Ss = 1024, Dd = 1024, Hh = 16, HDim = 64, Nn = 4096;
constexpr int Mm = Bb * Ss; // 4096

__device__ inline void gload_lds16(const void* g, void* l) {
  __builtin_amdgcn_global_load_lds(
      (const __attribute__((address_space(1))) void*)g,
      (__attribute__((address_space(3))) void*)l, 16, 0, 0);
}

// ---------------------------------------------------------------------------
// fp32 GEMM v7: C[M,N] = A[M,K] @ W[N,K]^T (+ bias[N]).
// 256 threads = 4 waves (2x2 quadrants of BM/2 x 64).
// TM=16: micro 16x8 per thread, BM=256. 6 ds_read_b128 per 128 FMA =
//   0.75 B/FMA-lane -> LDS-read cap rises from 66% (r10's 8x8, 1.0 B/FMA)
//   to ~89% of FMA peak. The 16 rows are TWO 8-row groups spaced 64 apart
//   (row0+0..7 and row0+64..71) so every A-read keeps the 2-way-free bank
//   pattern (a contiguous 16-row read would be 4-way conflicted).
//   __launch_bounds__(256,1): reg cap 512; live ~206 (acc 128 + 24 prefetch)
//   -> no spill (r5's TM=16 failed because (128,2) capped regs at 128).
// TM=4: micro 4x8, BM=64 (ctx GEMM: 512 blocks -> 2/CU). r10-validated.
// Schedule (r10-validated): double-buffered LDS, ONE barrier per tile,
// prefetch issued after the barrier -> vmcnt wait lands after the full
// compute phase.
// MODE 0: C = acc + bias.  MODE 2 (TM=16): partial[blockIdx.y][n] = max
// over the tile's 256 rows (feeds the router's pooled max; 4 tiles/batch).
// ---------------------------------------------------------------------------
template <int MODE, int TM>
__global__ __launch_bounds__(256, 1) void gemm_f32(
    const float* __restrict__ A, const float* __restrict__ W,
    const float* __restrict__ bias, float* __restrict__ C, const int K,
    const int ldc) {
  constexpr int BM = TM * 16;
  __shared__ float As[2][16][BM];
  __shared__ float Ws[2][16][128];
  __shared__ float red[2][128];
  const int tid = threadIdx.x;
  const int lane = tid & 63, wv = tid >> 6;
  const int wm = wv >> 1, wn = wv & 1;
  const int lty = lane >> 3, ltx = lane & 7;
  const int m0 = blockIdx.y * BM, n0 = blockIdx.x * 128;
  const int row0 = wm * (BM / 2) + lty * ((TM == 16) ? 8 : TM);
  const int col0 = wn * 64 + ltx * 8;
  // staging: TM=16 -> 1 thread per A row (16 floats); TM=4 -> 4 thr/row
  const int asrow = (TM == 16) ? tid : (tid >> 2);
  const int asoff = (TM == 16) ? 0 : ((tid & 3) * 4);
  const int bsrow = tid >> 1, bsoff = (tid & 1) * 8;
  const float* Ap = A + (size_t)(m0 + asrow) * K + asoff;
  const float* Wp = W + (size_t)(n0 + bsrow) * K + bsoff;

  // preload tile 0
  float4 ar[4], w0r, w1r;
  ar[0] = *(const float4*)(Ap);
  if constexpr (TM == 16) {
    ar[1] = *(const float4*)(Ap + 4);
    ar[2] = *(const float4*)(Ap + 8);
    ar[3] = *(const float4*)(Ap + 12);
  }
  w0r = *(const float4*)(Wp);
  w1r = *(const float4*)(Wp + 4);

  float acc[TM][8] = {};
  const int NT = K / 16;
#pragma unroll 1
  for (int kt = 0; kt < NT; ++kt) {
    float* Ab = &As[kt & 1][0][0];
    float* Wb = &Ws[kt & 1][0][0];
    // regs -> LDS (transposed [k][m]); implicit vmcnt wait for prefetched
    // regs sits here, one full compute phase after issue.
    if constexpr (TM == 16) {
#pragma unroll
      for (int c = 0; c < 16; ++c)
        Ab[c * BM + asrow] = ((const float*)ar)[c];
    } else {
      Ab[(asoff + 0) * BM + asrow] = ar[0].x;
      Ab[(asoff + 1) * BM + asrow] = ar[0].y;
      Ab[(asoff + 2) * BM + asrow] = ar[0].z;
      Ab[(asoff + 3) * BM + asrow] = ar[0].w;
    }
    Wb[(bsoff + 0) * 128 + bsrow] = w0r.x;
    Wb[(bsoff + 1) * 128 + bsrow] = w0r.y;
    Wb[(bsoff + 2) * 128 + bsrow] = w0r.z;
    Wb[(bsoff + 3) * 128 + bsrow] = w0r.w;
    Wb[(bsoff + 4) * 128 + bsrow] = w1r.x;
    Wb[(bsoff + 5) * 128 + bsrow] = w1r.y;
    Wb[(bsoff + 6) * 128 + bsrow] = w1r.z;
    Wb[(bsoff + 7) * 128 + bsrow] = w1r.w;
    __syncthreads();  // tile visible; single barrier per iteration
    if (kt + 1 < NT) {  // prefetch next tile; consumed after compute
      const int kb = (kt + 1) * 16;
      ar[0] = *(const float4*)(Ap + kb);
      if constexpr (TM == 16) {
        ar[1] = *(const float4*)(Ap + kb + 4);
        ar[2] = *(const float4*)(Ap + kb + 8);
        ar[3] = *(const float4*)(Ap + kb + 12);
      }
      w0r = *(const float4*)(Wp + kb);
      w1r = *(const float4*)(Wp + kb + 4);
    }
#pragma unroll
    for (int kk = 0; kk < 16; ++kk) {
      float av[TM];
      {
        float4 aq0 = *(const float4*)&Ab[kk * BM + row0];
        av[0] = aq0.x; av[1] = aq0.y; av[2] = aq0.z; av[3] = aq0.w;
      }
      if constexpr (TM == 16) {
        float4 aq1 = *(const float4*)&Ab[kk * BM + row0 + 4];
        float4 aq2 = *(const float4*)&Ab[kk * BM + row0 + 64];
        float4 aq3 = *(const float4*)&Ab[kk * BM + row0 + 68];
        av[4] = aq1.x; av[5] = aq1.y; av[6] = aq1.z; av[7] = aq1.w;
        av[8] = aq2.x; av[9] = aq2.y; av[10] = aq2.z; av[11] = aq2.w;
        av[12] = aq3.x; av[13] = aq3.y; av[14] = aq3.z; av[15] = aq3.w;
      }
      float4 bq0 = *(const float4*)&Wb[kk * 128 + col0];
      float4 bq1 = *(const float4*)&Wb[kk * 128 + col0 + 4];
      const float bv[8] = {bq0.x, bq0.y, bq0.z, bq0.w,
                           bq1.x, bq1.y, bq1.z, bq1.w};
#pragma unroll
      for (int i = 0; i < TM; ++i)
#pragma unroll
        for (int j = 0; j < 8; ++j)
          acc[i][j] = fmaf(av[i], bv[j], acc[i][j]);
    }
  }

  if constexpr (MODE == 0) {
    float4 bb0 = *(const float4*)&bias[n0 + col0];
    float4 bb1 = *(const float4*)&bias[n0 + col0 + 4];
    const float bvv[8] = {bb0.x, bb0.y, bb0.z, bb0.w,
                          bb1.x, bb1.y, bb1.z, bb1.w};
#pragma unroll
    for (int i = 0; i < TM; ++i) {
      const int roff = (TM == 16) ? ((i & 7) + (i >> 3) * 64) : i;
      float* crow = C + (size_t)(m0 + row0 + roff) * ldc + n0 + col0;
      float4 o0 = {acc[i][0] + bvv[0], acc[i][1] + bvv[1],
                   acc[i][2] + bvv[2], acc[i][3] + bvv[3]};
      float4 o1 = {acc[i][4] + bvv[4], acc[i][5] + bvv[5],
                   acc[i][6] + bvv[6], acc[i][7] + bvv[7]};
      *(float4*)(crow) = o0;
      *(float4*)(crow + 4) = o1;
    }
  } else {
    // column max over the tile's BM rows -> partial[blockIdx.y][n0+col]
    float cm[8];
#pragma unroll
    for (int j = 0; j < 8; ++j) {
      float m = acc[0][j];
#pragma unroll
      for (int i = 1; i < TM; ++i) m = fmaxf(m, acc[i][j]);
      m = fmaxf(m, __shfl_xor(m, 8));   // reduce over lty (lane bits 3..5)
      m = fmaxf(m, __shfl_xor(m, 16));
      m = fmaxf(m, __shfl_xor(m, 32));
      cm[j] = m;
    }
    __syncthreads();
    if (lty == 0) {
      float4 c0 = {cm[0], cm[1], cm[2], cm[3]};
      float4 c1 = {cm[4], cm[5], cm[6], cm[7]};
      *(float4*)&red[wm][wn * 64 + ltx * 8] = c0;
      *(float4*)&red[wm][wn * 64 + ltx * 8 + 4] = c1;
    }
    __syncthreads();
    if (tid < 128)
      C[(size_t)blockIdx.y * ldc + n0 + tid] =
          fmaxf(red[0][tid], red[1][tid]);
  }
}

// ---------------------------------------------------------------------------
// Flash attention v6 (validated r10): 4-wave blocks, shared K/V staged via
// global_load_lds (no VGPR round-trip -> no spills), double-buffered
// KVBLK=16 tiles, ONE barrier/tile, XCD-local grid (bh = id mod 64).
// ---------------------------------------------------------------------------
__device__ __forceinline__ int kkey(int r) { return ((r >> 3) ^ r) & 7; }
__device__ __forceinline__ int swz(int r, int c) { return c ^ (kkey(r) << 2); }
__device__ __forceinline__ int swzp(int r, int c) {
  return c ^ ((kkey(r) & 3) << 2);
}

__global__ __launch_bounds__(256, 2) void attn_kernel(
    const float* __restrict__ qkv, float* __restrict__ ctx) {
  __shared__ float Qs[4][32][64];  // 32 KB, wave-private quadrants
  __shared__ float Ks[2][16][64];  // 8 KB, shared, double-buffered
  __shared__ float Vs[2][16][64];  // 8 KB, shared, double-buffered
  __shared__ float Pw[4][32][16];  // 8 KB, wave-private P
  const int tid = threadIdx.x, wv = tid >> 6, lane = tid & 63;
  const int rg = lane >> 3, cg = lane & 7;
  const int id = blockIdx.x;
  const int qb = id >> 6, bh = id & 63;  // bh = id mod 64 -> XCD-local heads
  const int b = bh >> 4, h = bh & 15;
  const int q0 = qb * 128 + wv * 32;
  const size_t rstride = 3 * Dd;
  const float* qbp = qkv + (size_t)b * Ss * rstride + h * HDim;
  const float* kbp = qbp + Dd;
  const float* vbp = qbp + 2 * Dd;

  {
    const int r = lane >> 1, ch = (lane & 1) * 32;
    const float* qr = qbp + (size_t)(q0 + r) * rstride + ch;
#pragma unroll
    for (int c = 0; c < 32; c += 4)
      *(float4*)&Qs[wv][r][swz(r, ch + c)] = *(const float4*)(qr + c);
  }

  const int srow = lane >> 4;
  const int scol = (lane & 15) * 4;
#define STAGE_KV(KT, BF)                                                      \
  {                                                                           \
    _Pragma("unroll") for (int j = 0; j < 2; ++j) {                           \
      const int g = wv * 2 + j;                                               \
      const int rr = (g & 3) * 4 + srow;                                      \
      const int cc = swz(rr, scol);                                           \
      if (g < 4)                                                              \
        gload_lds16(kbp + (size_t)((KT) + rr) * rstride + cc,                 \
                    &Ks[BF][(g & 3) * 4][0]);                                 \
      else                                                                    \
        gload_lds16(vbp + (size_t)((KT) + rr) * rstride + cc,                 \
                    &Vs[BF][(g & 3) * 4][0]);                                 \
    }                                                                         \
  }

  STAGE_KV(0, 0);
  __syncthreads();  // prologue: tile 0 visible (drains vmcnt), Q staged

  float O[4][8] = {};
  float mr[4], lr[4];
#pragma unroll
  for (int i = 0; i < 4; ++i) { mr[i] = -INFINITY; lr[i] = 0.f; }

#pragma unroll 1
  for (int t = 0; t < Ss / 16; ++t) {
    const int cur = t & 1;
    if (t + 1 < Ss / 16) STAGE_KV((t + 1) * 16, cur ^ 1);
    float sc[4][2] = {};
#pragma unroll
    for (int d0 = 0; d0 < HDim; d0 += 4) {
      float4 qa[4], kv[2];
#pragma unroll
      for (int i = 0; i < 4; ++i) {
        const int r = rg * 4 + i;
        qa[i] = *(const float4*)&Qs[wv][r][swz(r, d0)];
      }
#pragma unroll
      for (int j = 0; j < 2; ++j) {
        const int r = cg * 2 + j;
        kv[j] = *(const float4*)&Ks[cur][r][swz(r, d0)];
      }
#pragma unroll
      for (int i = 0; i < 4; ++i)
#pragma unroll
        for (int j = 0; j < 2; ++j) {
          sc[i][j] = fmaf(qa[i].x, kv[j].x, sc[i][j]);
          sc[i][j] = fmaf(qa[i].y, kv[j].y, sc[i][j]);
          sc[i][j] = fmaf(qa[i].z, kv[j].z, sc[i][j]);
          sc[i][j] = fmaf(qa[i].w, kv[j].w, sc[i][j]);
        }
    }
#pragma unroll
    for (int i = 0; i < 4; ++i) {
      const float s0 = sc[i][0] * 0.125f, s1 = sc[i][1] * 0.125f;
      float tm = fmaxf(s0, s1);
      tm = fmaxf(tm, __shfl_xor(tm, 1));
      tm = fmaxf(tm, __shfl_xor(tm, 2));
      tm = fmaxf(tm, __shfl_xor(tm, 4));
      const float mnew = fmaxf(mr[i], tm);
      const float p0 = __expf(s0 - mnew), p1 = __expf(s1 - mnew);
      float rs = p0 + p1;
      rs += __shfl_xor(rs, 1);
      rs += __shfl_xor(rs, 2);
      rs += __shfl_xor(rs, 4);
      const float corr = __expf(mr[i] - mnew);
      lr[i] = lr[i] * corr + rs;
      mr[i] = mnew;
#pragma unroll
      for (int c = 0; c < 8; ++c) O[i][c] *= corr;
      const int r = rg * 4 + i;
      float2 pv = {p0, p1};
      *(float2*)&Pw[wv][r][swzp(r, cg * 2)] = pv;
    }
#pragma unroll
    for (int k0 = 0; k0 < 16; k0 += 4) {
      float4 pa[4];
#pragma unroll
      for (int i = 0; i < 4; ++i) {
        const int r = rg * 4 + i;
        pa[i] = *(const float4*)&Pw[wv][r][swzp(r, k0)];
      }
#pragma unroll
      for (int jj = 0; jj < 4; ++jj) {
        const int vr = k0 + jj;
        const float4 v0 = *(const float4*)&Vs[cur][vr][swz(vr, cg * 8)];
        const float4 v1 = *(const float4*)&Vs[cur][vr][swz(vr, cg * 8 + 4)];
#pragma unroll
        for (int i = 0; i < 4; ++i) {
          const float p = (jj == 0) ? pa[i].x
                          : (jj == 1) ? pa[i].y
                          : (jj == 2) ? pa[i].z : pa[i].w;
          O[i][0] = fmaf(p, v0.x, O[i][0]);
          O[i][1] = fmaf(p, v0.y, O[i][1]);
          O[i][2] = fmaf(p, v0.z, O[i][2]);
          O[i][3] = fmaf(p, v0.w, O[i][3]);
          O[i][4] = fmaf(p, v1.x, O[i][4]);
          O[i][5] = fmaf(p, v1.y, O[i][5]);
          O[i][6] = fmaf(p, v1.z, O[i][6]);
          O[i][7] = fmaf(p, v1.w, O[i][7]);
        }
      }
    }
    __syncthreads();
  }
#pragma unroll
  for (int i = 0; i < 4; ++i) {
    const float inv = 1.0f / lr[i];
    float* orow =
        ctx + ((size_t)(b * Ss + q0 + rg * 4 + i)) * Dd + h * HDim + cg * 8;
    float4 o0 = {O[i][0] * inv, O[i][1] * inv, O[i][2] * inv, O[i][3] * inv};
    float4 o1 = {O[i][4] * inv, O[i][5] * inv, O[i][6] * inv, O[i][7] * inv};
    *(float4*)(orow) = o0;
    *(float4*)(orow + 4) = o1;
  }
#undef STAGE_KV
}

// ---------------------------------------------------------------------------
// Router: bitonic full-sort of packed u64 keys (exact stable top-k).
// Pooled max now over 4 mtiles/batch (aff GEMM tile is 256 rows).
// ---------------------------------------------------------------------------
__device__ inline unsigned int f2s(float f) {
  unsigned int u = __float_as_uint(f);
  return (u >> 31) ? ~u : (u | 0x80000000u);
}
__device__ inline float s2f(unsigned int s) {
  unsigned int u = (s >> 31) ? (s & 0x7fffffffu) : ~s;
  return __uint_as_float(u);
}

__global__ __launch_bounds__(256) void router_kernel(
    const float* __restrict__ partial, const float* __restrict__ aff_b,
    const int* __restrict__ kp, float* __restrict__ out, int out_size) {
  __shared__ unsigned long long keys[Nn];  // 32 KB
  __shared__ float lorig[Nn];              // 16 KB
  __shared__ float rv[4];
  const int tid = threadIdx.x;
  const int b = blockIdx.x;
  const int kcount = *kp;
  float* idx_out = out;
  float* w_out = out + (out_size - Mm * Dd - Bb * Nn);
  for (int n = tid; n < Nn; n += 256) {
    float m = partial[(size_t)(b * 4) * Nn + n];
#pragma unroll
    for (int t = 1; t < 4; ++t)
      m = fmaxf(m, partial[(size_t)(b * 4 + t) * Nn + n]);
    float lg = (m + aff_b[n]) * 0.5f;  // /TEMPERATURE
    lorig[n] = lg;
    keys[n] = ((unsigned long long)f2s(lg) << 32) | (unsigned int)(Nn - 1 - n);
  }
  __syncthreads();
  for (int kk = 2; kk <= Nn; kk <<= 1) {
    for (int j = kk >> 1; j > 0; j >>= 1) {
#pragma unroll 4
      for (int t = tid; t < Nn / 2; t += 256) {
        const int i = 2 * j * (t / j) + (t % j);
        const int p = i + j;
        const bool desc = ((i & kk) == 0);
        unsigned long long a = keys[i], c = keys[p];
        if (desc ? (a < c) : (a > c)) { keys[i] = c; keys[p] = a; }
      }
      __syncthreads();
    }
  }
  const float gm = s2f((unsigned int)(keys[0] >> 32));
  float se = 0.f;
  for (int n = tid; n < Nn; n += 256) se += expf(lorig[n] - gm);
#pragma unroll
  for (int msk = 1; msk < 64; msk <<= 1) se += __shfl_xor(se, msk);
  if ((tid & 63) == 0) rv[tid >> 6] = se;
  __syncthreads();
  se = rv[0] + rv[1] + rv[2] + rv[3];
  __syncthreads();
  float es = 0.f;
  for (int p = tid; p < kcount; p += 256)
    es += expf(s2f((unsigned int)(keys[p] >> 32)) - gm);
#pragma unroll
  for (int msk = 1; msk < 64; msk <<= 1) es += __shfl_xor(es, msk);
  if ((tid & 63) == 0) rv[tid >> 6] = es;
  __syncthreads();
  es = rv[0] + rv[1] + rv[2] + rv[3];
  const float wd = es / se + 1e-8f;
  for (int n = tid; n < Nn; n += 256) w_out[(size_t)b * Nn + n] = 0.f;
  __syncthreads();
  for (int p = tid; p < kcount; p += 256) {
    const unsigned long long kkey2 = keys[p];
    const int n = Nn - 1 - (int)(kkey2 & 0xffffffffu);
    const float val = s2f((unsigned int)(kkey2 >> 32));
    idx_out[b * kcount + p] = (float)n;
    w_out[(size_t)b * Nn + n] = (expf(val - gm) / se) / wd;
  }
}

}  // namespace

extern "C" void kernel_launch(void* const* d_in, const int* in_sizes, int n_in,
                              void* d_out, int out_size, void* d_ws,
                              size_t ws_size, hipStream_t stream) {
  (void)in_sizes; (void)n_in; (void)ws_size;
  const float* x = (const float*)d_in[0];
  const float* in_proj_w = (const float*)d_in[1];
  const float* in_proj_b = (const float*)d_in[2];
  const float* out_w = (const float*)d_in[3];
  const float* out_b = (const float*)d_in[4];
  const float* aff_w = (const float*)d_in[5];
  const float* aff_b = (const float*)d_in[6];
  const int* kp = (const int*)d_in[7];

  float* qkv = (float*)d_ws;                 // [4096, 3072] = 50.3 MB
  float* ctxws = qkv + (size_t)Mm * 3 * Dd;  // [4096, 1024] = 16.8 MB
  float* partial = ctxws + (size_t)Mm * Dd;  // [16, 4096]   = 0.25 MB

  float* out = (float*)d_out;
  float* ctx_out = out + ((size_t)out_size - (size_t)Mm * Dd);  // context tail

  // 1) qkv = x @ in_proj_w^T + b   (BM=256: grid 24x16 = 384 blocks)
  gemm_f32<0, 16><<<dim3(3 * Dd / 128, Mm / 256), 256, 0, stream>>>(
      x, in_proj_w, in_proj_b, qkv, Dd, 3 * Dd);
  // 2) attention -> ctxws  (512 four-wave blocks, XCD-local)
  attn_kernel<<<dim3(Ss / 128 * Bb * Hh), 256, 0, stream>>>(qkv, ctxws);
  // 3) context = ctxws @ out_w^T + b  (BM=64 -> 512 blocks)
  gemm_f32<0, 4><<<dim3(Dd / 128, Mm / 64), 256, 0, stream>>>(
      ctxws, out_w, out_b, ctx_out, Dd, Dd);
  // 4) partial[mtile][n] = max over 256 rows of (context @ aff_w^T)
  gemm_f32<2, 16><<<dim3(Nn / 128, Mm / 256), 256, 0, stream>>>(
      ctx_out, aff_w, nullptr, partial, Dd, Nn);
  // 5) router: pooled max (4 tiles), softmax, exact top-k, weights
  router_kernel<<<dim3(Bb), 256, 0, stream>>>(partial, aff_b, kp, out, out_size);
}

// Round 12
// 1297.636 us; speedup vs baseline: 1.0774x; 1.0774x over previous
//
#include <hip/hip_runtime.h>
#include <math.h>

namespace {

constexpr int Bb = 4, Ss = 1024, Dd = 1024, Hh = 16, HDim = 64, Nn = 4096;
constexpr int Mm = Bb * Ss; // 4096

__device__ inline void gload_lds16(const void* g, void* l) {
  __builtin_amdgcn_global_load_lds(
      (const __attribute__((address_space(1))) void*)g,
      (__attribute__((address_space(3))) void*)l, 16, 0, 0);
}

// ---------------------------------------------------------------------------
// fp32 GEMM v8: C[M,N] = A[M,K] @ W[N,K]^T (+ bias[N]).
// 256 threads = 4 waves (2x2 quadrants of BM/2 x 64).
// TM=16 (BM=256, BK=8): 16x8 micro -> 6 ds_read_b128 per 128 FMA
//   (0.75 B/FMA-lane, LDS-issue cap ~85-89% of FMA peak). r11 lesson: at
//   BK=16 this tile needs 48 KB LDS -> 1 block/CU -> occupancy crash
//   (11.5%, VALUBusy 62%). BK=8 halves LDS to ~25 KB -> 2 blocks/CU
//   (8 waves, 25%), while per-barrier compute per thread stays 1024 FMA
//   (8 kk x 128) = identical barrier amortization to the r10 kernel.
//   16 rows = two 8-row groups spaced 64 apart -> A-reads stay 2-way free.
// TM=4 (BM=64, BK=16): ctx GEMM (512 blocks -> 2/CU). r10-validated.
// Schedule (r10-validated): double-buffered LDS, ONE barrier per tile,
// prefetch issued after the barrier -> vmcnt wait lands after the full
// compute phase. Reads of buf[cur] finish before its overwrite 2 barriers
// later.
// MODE 0: C = acc + bias.  MODE 2 (TM=16): partial[blockIdx.y][n] = max
// over the tile's 256 rows (router pooled max; 4 tiles/batch).
// ---------------------------------------------------------------------------
template <int MODE, int TM>
__global__ __launch_bounds__(256, 2) void gemm_f32(
    const float* __restrict__ A, const float* __restrict__ W,
    const float* __restrict__ bias, float* __restrict__ C, const int K,
    const int ldc) {
  constexpr int BM = TM * 16;
  constexpr int BK = (TM == 16) ? 8 : 16;
  __shared__ float As[2][BK][BM];
  __shared__ float Ws[2][BK][128];
  __shared__ float red[2][128];
  const int tid = threadIdx.x;
  const int lane = tid & 63, wv = tid >> 6;
  const int wm = wv >> 1, wn = wv & 1;
  const int lty = lane >> 3, ltx = lane & 7;
  const int m0 = blockIdx.y * BM, n0 = blockIdx.x * 128;
  const int row0 = wm * (BM / 2) + lty * ((TM == 16) ? 8 : TM);
  const int col0 = wn * 64 + ltx * 8;
  // staging mapping
  //  TM=16: A row tid, k 0..7 (2 f4); W row tid>>1, k (tid&1)*4 (1 f4)
  //  TM=4 : A row tid>>2, k (tid&3)*4 (1 f4); W row tid>>1, k (tid&1)*8 (2 f4)
  const int asrow = (TM == 16) ? tid : (tid >> 2);
  const int asoff = (TM == 16) ? 0 : ((tid & 3) * 4);
  const int bsrow = tid >> 1;
  const int bsoff = (TM == 16) ? ((tid & 1) * 4) : ((tid & 1) * 8);
  const float* Ap = A + (size_t)(m0 + asrow) * K + asoff;
  const float* Wp = W + (size_t)(n0 + bsrow) * K + bsoff;

  // preload tile 0
  float4 ar[2], w0r, w1r;
  ar[0] = *(const float4*)(Ap);
  if constexpr (TM == 16) ar[1] = *(const float4*)(Ap + 4);
  w0r = *(const float4*)(Wp);
  if constexpr (TM == 4) w1r = *(const float4*)(Wp + 4);

  float acc[TM][8] = {};
  const int NT = K / BK;
#pragma unroll 1
  for (int kt = 0; kt < NT; ++kt) {
    float* Ab = &As[kt & 1][0][0];
    float* Wb = &Ws[kt & 1][0][0];
    // regs -> LDS (transposed [k][m]); implicit vmcnt wait for prefetched
    // regs sits here, one full compute phase after issue.
    if constexpr (TM == 16) {
#pragma unroll
      for (int c = 0; c < 8; ++c) Ab[c * BM + asrow] = ((const float*)ar)[c];
      Wb[(bsoff + 0) * 128 + bsrow] = w0r.x;
      Wb[(bsoff + 1) * 128 + bsrow] = w0r.y;
      Wb[(bsoff + 2) * 128 + bsrow] = w0r.z;
      Wb[(bsoff + 3) * 128 + bsrow] = w0r.w;
    } else {
      Ab[(asoff + 0) * BM + asrow] = ar[0].x;
      Ab[(asoff + 1) * BM + asrow] = ar[0].y;
      Ab[(asoff + 2) * BM + asrow] = ar[0].z;
      Ab[(asoff + 3) * BM + asrow] = ar[0].w;
      Wb[(bsoff + 0) * 128 + bsrow] = w0r.x;
      Wb[(bsoff + 1) * 128 + bsrow] = w0r.y;
      Wb[(bsoff + 2) * 128 + bsrow] = w0r.z;
      Wb[(bsoff + 3) * 128 + bsrow] = w0r.w;
      Wb[(bsoff + 4) * 128 + bsrow] = w1r.x;
      Wb[(bsoff + 5) * 128 + bsrow] = w1r.y;
      Wb[(bsoff + 6) * 128 + bsrow] = w1r.z;
      Wb[(bsoff + 7) * 128 + bsrow] = w1r.w;
    }
    __syncthreads();  // tile visible; single barrier per iteration
    if (kt + 1 < NT) {  // prefetch next tile; consumed after compute
      const int kb = (kt + 1) * BK;
      ar[0] = *(const float4*)(Ap + kb);
      if constexpr (TM == 16) ar[1] = *(const float4*)(Ap + kb + 4);
      w0r = *(const float4*)(Wp + kb);
      if constexpr (TM == 4) w1r = *(const float4*)(Wp + kb + 4);
    }
#pragma unroll
    for (int kk = 0; kk < BK; ++kk) {
      float av[TM];
      {
        float4 aq0 = *(const float4*)&Ab[kk * BM + row0];
        av[0] = aq0.x; av[1] = aq0.y; av[2] = aq0.z; av[3] = aq0.w;
      }
      if constexpr (TM == 16) {
        float4 aq1 = *(const float4*)&Ab[kk * BM + row0 + 4];
        float4 aq2 = *(const float4*)&Ab[kk * BM + row0 + 64];
        float4 aq3 = *(const float4*)&Ab[kk * BM + row0 + 68];
        av[4] = aq1.x; av[5] = aq1.y; av[6] = aq1.z; av[7] = aq1.w;
        av[8] = aq2.x; av[9] = aq2.y; av[10] = aq2.z; av[11] = aq2.w;
        av[12] = aq3.x; av[13] = aq3.y; av[14] = aq3.z; av[15] = aq3.w;
      }
      float4 bq0 = *(const float4*)&Wb[kk * 128 + col0];
      float4 bq1 = *(const float4*)&Wb[kk * 128 + col0 + 4];
      const float bv[8] = {bq0.x, bq0.y, bq0.z, bq0.w,
                           bq1.x, bq1.y, bq1.z, bq1.w};
#pragma unroll
      for (int i = 0; i < TM; ++i)
#pragma unroll
        for (int j = 0; j < 8; ++j)
          acc[i][j] = fmaf(av[i], bv[j], acc[i][j]);
    }
  }

  if constexpr (MODE == 0) {
    float4 bb0 = *(const float4*)&bias[n0 + col0];
    float4 bb1 = *(const float4*)&bias[n0 + col0 + 4];
    const float bvv[8] = {bb0.x, bb0.y, bb0.z, bb0.w,
                          bb1.x, bb1.y, bb1.z, bb1.w};
#pragma unroll
    for (int i = 0; i < TM; ++i) {
      const int roff = (TM == 16) ? ((i & 7) + (i >> 3) * 64) : i;
      float* crow = C + (size_t)(m0 + row0 + roff) * ldc + n0 + col0;
      float4 o0 = {acc[i][0] + bvv[0], acc[i][1] + bvv[1],
                   acc[i][2] + bvv[2], acc[i][3] + bvv[3]};
      float4 o1 = {acc[i][4] + bvv[4], acc[i][5] + bvv[5],
                   acc[i][6] + bvv[6], acc[i][7] + bvv[7]};
      *(float4*)(crow) = o0;
      *(float4*)(crow + 4) = o1;
    }
  } else {
    // column max over the tile's BM rows -> partial[blockIdx.y][n0+col]
    float cm[8];
#pragma unroll
    for (int j = 0; j < 8; ++j) {
      float m = acc[0][j];
#pragma unroll
      for (int i = 1; i < TM; ++i) m = fmaxf(m, acc[i][j]);
      m = fmaxf(m, __shfl_xor(m, 8));   // reduce over lty (lane bits 3..5)
      m = fmaxf(m, __shfl_xor(m, 16));
      m = fmaxf(m, __shfl_xor(m, 32));
      cm[j] = m;
    }
    __syncthreads();
    if (lty == 0) {
      float4 c0 = {cm[0], cm[1], cm[2], cm[3]};
      float4 c1 = {cm[4], cm[5], cm[6], cm[7]};
      *(float4*)&red[wm][wn * 64 + ltx * 8] = c0;
      *(float4*)&red[wm][wn * 64 + ltx * 8 + 4] = c1;
    }
    __syncthreads();
    if (tid < 128)
      C[(size_t)blockIdx.y * ldc + n0 + tid] =
          fmaxf(red[0][tid], red[1][tid]);
  }
}

// ---------------------------------------------------------------------------
// Flash attention v6 (validated r10): 4-wave blocks, shared K/V staged via
// global_load_lds (no VGPR round-trip -> no spills), double-buffered
// KVBLK=16 tiles, ONE barrier/tile, XCD-local grid (bh = id mod 64).
// ---------------------------------------------------------------------------
__device__ __forceinline__ int kkey(int r) { return ((r >> 3) ^ r) & 7; }
__device__ __forceinline__ int swz(int r, int c) { return c ^ (kkey(r) << 2); }
__device__ __forceinline__ int swzp(int r, int c) {
  return c ^ ((kkey(r) & 3) << 2);
}

__global__ __launch_bounds__(256, 2) void attn_kernel(
    const float* __restrict__ qkv, float* __restrict__ ctx) {
  __shared__ float Qs[4][32][64];  // 32 KB, wave-private quadrants
  __shared__ float Ks[2][16][64];  // 8 KB, shared, double-buffered
  __shared__ float Vs[2][16][64];  // 8 KB, shared, double-buffered
  __shared__ float Pw[4][32][16];  // 8 KB, wave-private P
  const int tid = threadIdx.x, wv = tid >> 6, lane = tid & 63;
  const int rg = lane >> 3, cg = lane & 7;
  const int id = blockIdx.x;
  const int qb = id >> 6, bh = id & 63;  // bh = id mod 64 -> XCD-local heads
  const int b = bh >> 4, h = bh & 15;
  const int q0 = qb * 128 + wv * 32;
  const size_t rstride = 3 * Dd;
  const float* qbp = qkv + (size_t)b * Ss * rstride + h * HDim;
  const float* kbp = qbp + Dd;
  const float* vbp = qbp + 2 * Dd;

  {
    const int r = lane >> 1, ch = (lane & 1) * 32;
    const float* qr = qbp + (size_t)(q0 + r) * rstride + ch;
#pragma unroll
    for (int c = 0; c < 32; c += 4)
      *(float4*)&Qs[wv][r][swz(r, ch + c)] = *(const float4*)(qr + c);
  }

  const int srow = lane >> 4;
  const int scol = (lane & 15) * 4;
#define STAGE_KV(KT, BF)                                                      \
  {                                                                           \
    _Pragma("unroll") for (int j = 0; j < 2; ++j) {                           \
      const int g = wv * 2 + j;                                               \
      const int rr = (g & 3) * 4 + srow;                                      \
      const int cc = swz(rr, scol);                                           \
      if (g < 4)                                                              \
        gload_lds16(kbp + (size_t)((KT) + rr) * rstride + cc,                 \
                    &Ks[BF][(g & 3) * 4][0]);                                 \
      else                                                                    \
        gload_lds16(vbp + (size_t)((KT) + rr) * rstride + cc,                 \
                    &Vs[BF][(g & 3) * 4][0]);                                 \
    }                                                                         \
  }

  STAGE_KV(0, 0);
  __syncthreads();  // prologue: tile 0 visible (drains vmcnt), Q staged

  float O[4][8] = {};
  float mr[4], lr[4];
#pragma unroll
  for (int i = 0; i < 4; ++i) { mr[i] = -INFINITY; lr[i] = 0.f; }

#pragma unroll 1
  for (int t = 0; t < Ss / 16; ++t) {
    const int cur = t & 1;
    if (t + 1 < Ss / 16) STAGE_KV((t + 1) * 16, cur ^ 1);
    float sc[4][2] = {};
#pragma unroll
    for (int d0 = 0; d0 < HDim; d0 += 4) {
      float4 qa[4], kv[2];
#pragma unroll
      for (int i = 0; i < 4; ++i) {
        const int r = rg * 4 + i;
        qa[i] = *(const float4*)&Qs[wv][r][swz(r, d0)];
      }
#pragma unroll
      for (int j = 0; j < 2; ++j) {
        const int r = cg * 2 + j;
        kv[j] = *(const float4*)&Ks[cur][r][swz(r, d0)];
      }
#pragma unroll
      for (int i = 0; i < 4; ++i)
#pragma unroll
        for (int j = 0; j < 2; ++j) {
          sc[i][j] = fmaf(qa[i].x, kv[j].x, sc[i][j]);
          sc[i][j] = fmaf(qa[i].y, kv[j].y, sc[i][j]);
          sc[i][j] = fmaf(qa[i].z, kv[j].z, sc[i][j]);
          sc[i][j] = fmaf(qa[i].w, kv[j].w, sc[i][j]);
        }
    }
#pragma unroll
    for (int i = 0; i < 4; ++i) {
      const float s0 = sc[i][0] * 0.125f, s1 = sc[i][1] * 0.125f;
      float tm = fmaxf(s0, s1);
      tm = fmaxf(tm, __shfl_xor(tm, 1));
      tm = fmaxf(tm, __shfl_xor(tm, 2));
      tm = fmaxf(tm, __shfl_xor(tm, 4));
      const float mnew = fmaxf(mr[i], tm);
      const float p0 = __expf(s0 - mnew), p1 = __expf(s1 - mnew);
      float rs = p0 + p1;
      rs += __shfl_xor(rs, 1);
      rs += __shfl_xor(rs, 2);
      rs += __shfl_xor(rs, 4);
      const float corr = __expf(mr[i] - mnew);
      lr[i] = lr[i] * corr + rs;
      mr[i] = mnew;
#pragma unroll
      for (int c = 0; c < 8; ++c) O[i][c] *= corr;
      const int r = rg * 4 + i;
      float2 pv = {p0, p1};
      *(float2*)&Pw[wv][r][swzp(r, cg * 2)] = pv;
    }
#pragma unroll
    for (int k0 = 0; k0 < 16; k0 += 4) {
      float4 pa[4];
#pragma unroll
      for (int i = 0; i < 4; ++i) {
        const int r = rg * 4 + i;
        pa[i] = *(const float4*)&Pw[wv][r][swzp(r, k0)];
      }
#pragma unroll
      for (int jj = 0; jj < 4; ++jj) {
        const int vr = k0 + jj;
        const float4 v0 = *(const float4*)&Vs[cur][vr][swz(vr, cg * 8)];
        const float4 v1 = *(const float4*)&Vs[cur][vr][swz(vr, cg * 8 + 4)];
#pragma unroll
        for (int i = 0; i < 4; ++i) {
          const float p = (jj == 0) ? pa[i].x
                          : (jj == 1) ? pa[i].y
                          : (jj == 2) ? pa[i].z : pa[i].w;
          O[i][0] = fmaf(p, v0.x, O[i][0]);
          O[i][1] = fmaf(p, v0.y, O[i][1]);
          O[i][2] = fmaf(p, v0.z, O[i][2]);
          O[i][3] = fmaf(p, v0.w, O[i][3]);
          O[i][4] = fmaf(p, v1.x, O[i][4]);
          O[i][5] = fmaf(p, v1.y, O[i][5]);
          O[i][6] = fmaf(p, v1.z, O[i][6]);
          O[i][7] = fmaf(p, v1.w, O[i][7]);
        }
      }
    }
    __syncthreads();
  }
#pragma unroll
  for (int i = 0; i < 4; ++i) {
    const float inv = 1.0f / lr[i];
    float* orow =
        ctx + ((size_t)(b * Ss + q0 + rg * 4 + i)) * Dd + h * HDim + cg * 8;
    float4 o0 = {O[i][0] * inv, O[i][1] * inv, O[i][2] * inv, O[i][3] * inv};
    float4 o1 = {O[i][4] * inv, O[i][5] * inv, O[i][6] * inv, O[i][7] * inv};
    *(float4*)(orow) = o0;
    *(float4*)(orow + 4) = o1;
  }
#undef STAGE_KV
}

// ---------------------------------------------------------------------------
// Router: bitonic full-sort of packed u64 keys (exact stable top-k).
// Pooled max over 4 mtiles/batch (aff GEMM tile is 256 rows).
// ---------------------------------------------------------------------------
__device__ inline unsigned int f2s(float f) {
  unsigned int u = __float_as_uint(f);
  return (u >> 31) ? ~u : (u | 0x80000000u);
}
__device__ inline float s2f(unsigned int s) {
  unsigned int u = (s >> 31) ? (s & 0x7fffffffu) : ~s;
  return __uint_as_float(u);
}

__global__ __launch_bounds__(256) void router_kernel(
    const float* __restrict__ partial, const float* __restrict__ aff_b,
    const int* __restrict__ kp, float* __restrict__ out, int out_size) {
  __shared__ unsigned long long keys[Nn];  // 32 KB
  __shared__ float lorig[Nn];              // 16 KB
  __shared__ float rv[4];
  const int tid = threadIdx.x;
  const int b = blockIdx.x;
  const int kcount = *kp;
  float* idx_out = out;
  float* w_out = out + (out_size - Mm * Dd - Bb * Nn);
  for (int n = tid; n < Nn; n += 256) {
    float m = partial[(size_t)(b * 4) * Nn + n];
#pragma unroll
    for (int t = 1; t < 4; ++t)
      m = fmaxf(m, partial[(size_t)(b * 4 + t) * Nn + n]);
    float lg = (m + aff_b[n]) * 0.5f;  // /TEMPERATURE
    lorig[n] = lg;
    keys[n] = ((unsigned long long)f2s(lg) << 32) | (unsigned int)(Nn - 1 - n);
  }
  __syncthreads();
  for (int kk = 2; kk <= Nn; kk <<= 1) {
    for (int j = kk >> 1; j > 0; j >>= 1) {
#pragma unroll 4
      for (int t = tid; t < Nn / 2; t += 256) {
        const int i = 2 * j * (t / j) + (t % j);
        const int p = i + j;
        const bool desc = ((i & kk) == 0);
        unsigned long long a = keys[i], c = keys[p];
        if (desc ? (a < c) : (a > c)) { keys[i] = c; keys[p] = a; }
      }
      __syncthreads();
    }
  }
  const float gm = s2f((unsigned int)(keys[0] >> 32));
  float se = 0.f;
  for (int n = tid; n < Nn; n += 256) se += expf(lorig[n] - gm);
#pragma unroll
  for (int msk = 1; msk < 64; msk <<= 1) se += __shfl_xor(se, msk);
  if ((tid & 63) == 0) rv[tid >> 6] = se;
  __syncthreads();
  se = rv[0] + rv[1] + rv[2] + rv[3];
  __syncthreads();
  float es = 0.f;
  for (int p = tid; p < kcount; p += 256)
    es += expf(s2f((unsigned int)(keys[p] >> 32)) - gm);
#pragma unroll
  for (int msk = 1; msk < 64; msk <<= 1) es += __shfl_xor(es, msk);
  if ((tid & 63) == 0) rv[tid >> 6] = es;
  __syncthreads();
  es = rv[0] + rv[1] + rv[2] + rv[3];
  const float wd = es / se + 1e-8f;
  for (int n = tid; n < Nn; n += 256) w_out[(size_t)b * Nn + n] = 0.f;
  __syncthreads();
  for (int p = tid; p < kcount; p += 256) {
    const unsigned long long kkey2 = keys[p];
    const int n = Nn - 1 - (int)(kkey2 & 0xffffffffu);
    const float val = s2f((unsigned int)(kkey2 >> 32));
    idx_out[b * kcount + p] = (float)n;
    w_out[(size_t)b * Nn + n] = (expf(val - gm) / se) / wd;
  }
}

}  // namespace

extern "C" void kernel_launch(void* const* d_in, const int* in_sizes, int n_in,
                              void* d_out, int out_size, void* d_ws,
                              size_t ws_size, hipStream_t stream) {
  (void)in_sizes; (void)n_in; (void)ws_size;
  const float* x = (const float*)d_in[0];
  const float* in_proj_w = (const float*)d_in[1];
  const float* in_proj_b = (const float*)d_in[2];
  const float* out_w = (const float*)d_in[3];
  const float* out_b = (const float*)d_in[4];
  const float* aff_w = (const float*)d_in[5];
  const float* aff_b = (const float*)d_in[6];
  const int* kp = (const int*)d_in[7];

  float* qkv = (float*)d_ws;                 // [4096, 3072] = 50.3 MB
  float* ctxws = qkv + (size_t)Mm * 3 * Dd;  // [4096, 1024] = 16.8 MB
  float* partial = ctxws + (size_t)Mm * Dd;  // [16, 4096]   = 0.25 MB

  float* out = (float*)d_out;
  float* ctx_out = out + ((size_t)out_size - (size_t)Mm * Dd);  // context tail

  // 1) qkv = x @ in_proj_w^T + b   (BM=256/BK=8: grid 24x16 = 384 blocks)
  gemm_f32<0, 16><<<dim3(3 * Dd / 128, Mm / 256), 256, 0, stream>>>(
      x, in_proj_w, in_proj_b, qkv, Dd, 3 * Dd);
  // 2) attention -> ctxws  (512 four-wave blocks, XCD-local)
  attn_kernel<<<dim3(Ss / 128 * Bb * Hh), 256, 0, stream>>>(qkv, ctxws);
  // 3) context = ctxws @ out_w^T + b  (BM=64 -> 512 blocks)
  gemm_f32<0, 4><<<dim3(Dd / 128, Mm / 64), 256, 0, stream>>>(
      ctxws, out_w, out_b, ctx_out, Dd, Dd);
  // 4) partial[mtile][n] = max over 256 rows of (context @ aff_w^T)
  gemm_f32<2, 16><<<dim3(Nn / 128, Mm / 256), 256, 0, stream>>>(
      ctx_out, aff_w, nullptr, partial, Dd, Nn);
  // 5) router: pooled max (4 tiles), softmax, exact top-k, weights
  router_kernel<<<dim3(Bb), 256, 0, stream>>>(partial, aff_b, kp, out, out_size);
}

// Round 13
// 1246.997 us; speedup vs baseline: 1.1212x; 1.0406x over previous
//
#include <hip/hip_runtime.h>
#include <math.h>

namespace {

constexpr int Bb = 4, Ss = 1024, Dd = 1024, Hh = 16, HDim = 64, Nn = 4096;
constexpr int Mm = Bb * Ss; // 4096

__device__ inline void gload_lds16(const void* g, void* l) {
  __builtin_amdgcn_global_load_lds(
      (const __attribute__((address_space(1))) void*)g,
      (__attribute__((address_space(3))) void*)l, 16, 0, 0);
}

// ---------------------------------------------------------------------------
// fp32 GEMM v9: C[M,N] = A[M,K] @ W[N,K]^T (+ bias[N]).
// 256 threads = 4 waves (2x2 quadrants of BM/2 x 64).
// TM=16 (BM=256, BK=8): 16x8 micro, 0.75 B/FMA-lane, 25.6 KB LDS ->
//   2 blocks/CU. r12-validated (aff: 408us, VALU 70%, no spills).
//   USE ONLY where grid = multiple of 512 blocks (aff: 32x16=512).
// TM=8  (BM=128, BK=16): 8x8 micro, r10-validated. For qkv: 24x32=768
//   blocks = balanced 2-resident/CU (r12 ran qkv at TM=16 -> 384 blocks =
//   1.5/CU imbalance, ~25% waste on the biggest GEMM -- reverted).
// TM=4  (BM=64, BK=16): ctx GEMM (512 blocks). r10-validated.
// Schedule (validated): double-buffered LDS, ONE barrier per tile,
// prefetch issued after the barrier -> vmcnt wait lands after the full
// compute phase.
// MODE 0: C = acc + bias.  MODE 2 (TM=16): partial[blockIdx.y][n] = max
// over the tile's 256 rows (router pooled max; 4 tiles/batch).
// ---------------------------------------------------------------------------
template <int MODE, int TM>
__global__ __launch_bounds__(256, 2) void gemm_f32(
    const float* __restrict__ A, const float* __restrict__ W,
    const float* __restrict__ bias, float* __restrict__ C, const int K,
    const int ldc) {
  constexpr int BM = TM * 16;
  constexpr int BK = (TM == 16) ? 8 : 16;
  __shared__ float As[2][BK][BM];
  __shared__ float Ws[2][BK][128];
  __shared__ float red[2][128];
  const int tid = threadIdx.x;
  const int lane = tid & 63, wv = tid >> 6;
  const int wm = wv >> 1, wn = wv & 1;
  const int lty = lane >> 3, ltx = lane & 7;
  const int m0 = blockIdx.y * BM, n0 = blockIdx.x * 128;
  const int row0 = wm * (BM / 2) + lty * ((TM == 16) ? 8 : TM);
  const int col0 = wn * 64 + ltx * 8;
  // staging mapping
  //  TM=16: A row tid, k 0..7 (2 f4);       W row tid>>1, k (tid&1)*4 (1 f4)
  //  TM=8 : A row tid>>1, k (tid&1)*8 (2 f4); W row tid>>1, k (tid&1)*8 (2 f4)
  //  TM=4 : A row tid>>2, k (tid&3)*4 (1 f4); W row tid>>1, k (tid&1)*8 (2 f4)
  const int asrow = (TM == 16) ? tid : ((TM == 8) ? (tid >> 1) : (tid >> 2));
  const int asoff = (TM == 16) ? 0
                    : ((TM == 8) ? ((tid & 1) * 8) : ((tid & 3) * 4));
  const int bsrow = tid >> 1;
  const int bsoff = (TM == 16) ? ((tid & 1) * 4) : ((tid & 1) * 8);
  const float* Ap = A + (size_t)(m0 + asrow) * K + asoff;
  const float* Wp = W + (size_t)(n0 + bsrow) * K + bsoff;

  // preload tile 0
  float4 ar[2], w0r, w1r;
  ar[0] = *(const float4*)(Ap);
  if constexpr (TM >= 8) ar[1] = *(const float4*)(Ap + 4);
  w0r = *(const float4*)(Wp);
  if constexpr (TM != 16) w1r = *(const float4*)(Wp + 4);

  float acc[TM][8] = {};
  const int NT = K / BK;
#pragma unroll 1
  for (int kt = 0; kt < NT; ++kt) {
    float* Ab = &As[kt & 1][0][0];
    float* Wb = &Ws[kt & 1][0][0];
    // regs -> LDS (transposed [k][m]); implicit vmcnt wait for prefetched
    // regs sits here, one full compute phase after issue.
    if constexpr (TM == 16) {
#pragma unroll
      for (int c = 0; c < 8; ++c) Ab[c * BM + asrow] = ((const float*)ar)[c];
      Wb[(bsoff + 0) * 128 + bsrow] = w0r.x;
      Wb[(bsoff + 1) * 128 + bsrow] = w0r.y;
      Wb[(bsoff + 2) * 128 + bsrow] = w0r.z;
      Wb[(bsoff + 3) * 128 + bsrow] = w0r.w;
    } else if constexpr (TM == 8) {
#pragma unroll
      for (int c = 0; c < 8; ++c)
        Ab[(asoff + c) * BM + asrow] = ((const float*)ar)[c];
      Wb[(bsoff + 0) * 128 + bsrow] = w0r.x;
      Wb[(bsoff + 1) * 128 + bsrow] = w0r.y;
      Wb[(bsoff + 2) * 128 + bsrow] = w0r.z;
      Wb[(bsoff + 3) * 128 + bsrow] = w0r.w;
      Wb[(bsoff + 4) * 128 + bsrow] = w1r.x;
      Wb[(bsoff + 5) * 128 + bsrow] = w1r.y;
      Wb[(bsoff + 6) * 128 + bsrow] = w1r.z;
      Wb[(bsoff + 7) * 128 + bsrow] = w1r.w;
    } else {
      Ab[(asoff + 0) * BM + asrow] = ar[0].x;
      Ab[(asoff + 1) * BM + asrow] = ar[0].y;
      Ab[(asoff + 2) * BM + asrow] = ar[0].z;
      Ab[(asoff + 3) * BM + asrow] = ar[0].w;
      Wb[(bsoff + 0) * 128 + bsrow] = w0r.x;
      Wb[(bsoff + 1) * 128 + bsrow] = w0r.y;
      Wb[(bsoff + 2) * 128 + bsrow] = w0r.z;
      Wb[(bsoff + 3) * 128 + bsrow] = w0r.w;
      Wb[(bsoff + 4) * 128 + bsrow] = w1r.x;
      Wb[(bsoff + 5) * 128 + bsrow] = w1r.y;
      Wb[(bsoff + 6) * 128 + bsrow] = w1r.z;
      Wb[(bsoff + 7) * 128 + bsrow] = w1r.w;
    }
    __syncthreads();  // tile visible; single barrier per iteration
    if (kt + 1 < NT) {  // prefetch next tile; consumed after compute
      const int kb = (kt + 1) * BK;
      ar[0] = *(const float4*)(Ap + kb);
      if constexpr (TM >= 8) ar[1] = *(const float4*)(Ap + kb + 4);
      w0r = *(const float4*)(Wp + kb);
      if constexpr (TM != 16) w1r = *(const float4*)(Wp + kb + 4);
    }
#pragma unroll
    for (int kk = 0; kk < BK; ++kk) {
      float av[TM];
      {
        float4 aq0 = *(const float4*)&Ab[kk * BM + row0];
        av[0] = aq0.x; av[1] = aq0.y; av[2] = aq0.z; av[3] = aq0.w;
      }
      if constexpr (TM >= 8) {
        float4 aq1 = *(const float4*)&Ab[kk * BM + row0 + 4];
        av[4] = aq1.x; av[5] = aq1.y; av[6] = aq1.z; av[7] = aq1.w;
      }
      if constexpr (TM == 16) {
        float4 aq2 = *(const float4*)&Ab[kk * BM + row0 + 64];
        float4 aq3 = *(const float4*)&Ab[kk * BM + row0 + 68];
        av[8] = aq2.x; av[9] = aq2.y; av[10] = aq2.z; av[11] = aq2.w;
        av[12] = aq3.x; av[13] = aq3.y; av[14] = aq3.z; av[15] = aq3.w;
      }
      float4 bq0 = *(const float4*)&Wb[kk * 128 + col0];
      float4 bq1 = *(const float4*)&Wb[kk * 128 + col0 + 4];
      const float bv[8] = {bq0.x, bq0.y, bq0.z, bq0.w,
                           bq1.x, bq1.y, bq1.z, bq1.w};
#pragma unroll
      for (int i = 0; i < TM; ++i)
#pragma unroll
        for (int j = 0; j < 8; ++j)
          acc[i][j] = fmaf(av[i], bv[j], acc[i][j]);
    }
  }

  if constexpr (MODE == 0) {
    float4 bb0 = *(const float4*)&bias[n0 + col0];
    float4 bb1 = *(const float4*)&bias[n0 + col0 + 4];
    const float bvv[8] = {bb0.x, bb0.y, bb0.z, bb0.w,
                          bb1.x, bb1.y, bb1.z, bb1.w};
#pragma unroll
    for (int i = 0; i < TM; ++i) {
      const int roff = (TM == 16) ? ((i & 7) + (i >> 3) * 64) : i;
      float* crow = C + (size_t)(m0 + row0 + roff) * ldc + n0 + col0;
      float4 o0 = {acc[i][0] + bvv[0], acc[i][1] + bvv[1],
                   acc[i][2] + bvv[2], acc[i][3] + bvv[3]};
      float4 o1 = {acc[i][4] + bvv[4], acc[i][5] + bvv[5],
                   acc[i][6] + bvv[6], acc[i][7] + bvv[7]};
      *(float4*)(crow) = o0;
      *(float4*)(crow + 4) = o1;
    }
  } else {
    // column max over the tile's BM rows -> partial[blockIdx.y][n0+col]
    float cm[8];
#pragma unroll
    for (int j = 0; j < 8; ++j) {
      float m = acc[0][j];
#pragma unroll
      for (int i = 1; i < TM; ++i) m = fmaxf(m, acc[i][j]);
      m = fmaxf(m, __shfl_xor(m, 8));   // reduce over lty (lane bits 3..5)
      m = fmaxf(m, __shfl_xor(m, 16));
      m = fmaxf(m, __shfl_xor(m, 32));
      cm[j] = m;
    }
    __syncthreads();
    if (lty == 0) {
      float4 c0 = {cm[0], cm[1], cm[2], cm[3]};
      float4 c1 = {cm[4], cm[5], cm[6], cm[7]};
      *(float4*)&red[wm][wn * 64 + ltx * 8] = c0;
      *(float4*)&red[wm][wn * 64 + ltx * 8 + 4] = c1;
    }
    __syncthreads();
    if (tid < 128)
      C[(size_t)blockIdx.y * ldc + n0 + tid] =
          fmaxf(red[0][tid], red[1][tid]);
  }
}

// ---------------------------------------------------------------------------
// Flash attention v6 (validated r10/r12): 4-wave blocks, shared K/V staged
// via global_load_lds (no spills), double-buffered KVBLK=16 tiles, ONE
// barrier/tile, XCD-local grid (bh = id mod 64).
// ---------------------------------------------------------------------------
__device__ __forceinline__ int kkey(int r) { return ((r >> 3) ^ r) & 7; }
__device__ __forceinline__ int swz(int r, int c) { return c ^ (kkey(r) << 2); }
__device__ __forceinline__ int swzp(int r, int c) {
  return c ^ ((kkey(r) & 3) << 2);
}

__global__ __launch_bounds__(256, 2) void attn_kernel(
    const float* __restrict__ qkv, float* __restrict__ ctx) {
  __shared__ float Qs[4][32][64];  // 32 KB, wave-private quadrants
  __shared__ float Ks[2][16][64];  // 8 KB, shared, double-buffered
  __shared__ float Vs[2][16][64];  // 8 KB, shared, double-buffered
  __shared__ float Pw[4][32][16];  // 8 KB, wave-private P
  const int tid = threadIdx.x, wv = tid >> 6, lane = tid & 63;
  const int rg = lane >> 3, cg = lane & 7;
  const int id = blockIdx.x;
  const int qb = id >> 6, bh = id & 63;  // bh = id mod 64 -> XCD-local heads
  const int b = bh >> 4, h = bh & 15;
  const int q0 = qb * 128 + wv * 32;
  const size_t rstride = 3 * Dd;
  const float* qbp = qkv + (size_t)b * Ss * rstride + h * HDim;
  const float* kbp = qbp + Dd;
  const float* vbp = qbp + 2 * Dd;

  {
    const int r = lane >> 1, ch = (lane & 1) * 32;
    const float* qr = qbp + (size_t)(q0 + r) * rstride + ch;
#pragma unroll
    for (int c = 0; c < 32; c += 4)
      *(float4*)&Qs[wv][r][swz(r, ch + c)] = *(const float4*)(qr + c);
  }

  const int srow = lane >> 4;
  const int scol = (lane & 15) * 4;
#define STAGE_KV(KT, BF)                                                      \
  {                                                                           \
    _Pragma("unroll") for (int j = 0; j < 2; ++j) {                           \
      const int g = wv * 2 + j;                                               \
      const int rr = (g & 3) * 4 + srow;                                      \
      const int cc = swz(rr, scol);                                           \
      if (g < 4)                                                              \
        gload_lds16(kbp + (size_t)((KT) + rr) * rstride + cc,                 \
                    &Ks[BF][(g & 3) * 4][0]);                                 \
      else                                                                    \
        gload_lds16(vbp + (size_t)((KT) + rr) * rstride + cc,                 \
                    &Vs[BF][(g & 3) * 4][0]);                                 \
    }                                                                         \
  }

  STAGE_KV(0, 0);
  __syncthreads();  // prologue: tile 0 visible (drains vmcnt), Q staged

  float O[4][8] = {};
  float mr[4], lr[4];
#pragma unroll
  for (int i = 0; i < 4; ++i) { mr[i] = -INFINITY; lr[i] = 0.f; }

#pragma unroll 1
  for (int t = 0; t < Ss / 16; ++t) {
    const int cur = t & 1;
    if (t + 1 < Ss / 16) STAGE_KV((t + 1) * 16, cur ^ 1);
    float sc[4][2] = {};
#pragma unroll
    for (int d0 = 0; d0 < HDim; d0 += 4) {
      float4 qa[4], kv[2];
#pragma unroll
      for (int i = 0; i < 4; ++i) {
        const int r = rg * 4 + i;
        qa[i] = *(const float4*)&Qs[wv][r][swz(r, d0)];
      }
#pragma unroll
      for (int j = 0; j < 2; ++j) {
        const int r = cg * 2 + j;
        kv[j] = *(const float4*)&Ks[cur][r][swz(r, d0)];
      }
#pragma unroll
      for (int i = 0; i < 4; ++i)
#pragma unroll
        for (int j = 0; j < 2; ++j) {
          sc[i][j] = fmaf(qa[i].x, kv[j].x, sc[i][j]);
          sc[i][j] = fmaf(qa[i].y, kv[j].y, sc[i][j]);
          sc[i][j] = fmaf(qa[i].z, kv[j].z, sc[i][j]);
          sc[i][j] = fmaf(qa[i].w, kv[j].w, sc[i][j]);
        }
    }
#pragma unroll
    for (int i = 0; i < 4; ++i) {
      const float s0 = sc[i][0] * 0.125f, s1 = sc[i][1] * 0.125f;
      float tm = fmaxf(s0, s1);
      tm = fmaxf(tm, __shfl_xor(tm, 1));
      tm = fmaxf(tm, __shfl_xor(tm, 2));
      tm = fmaxf(tm, __shfl_xor(tm, 4));
      const float mnew = fmaxf(mr[i], tm);
      const float p0 = __expf(s0 - mnew), p1 = __expf(s1 - mnew);
      float rs = p0 + p1;
      rs += __shfl_xor(rs, 1);
      rs += __shfl_xor(rs, 2);
      rs += __shfl_xor(rs, 4);
      const float corr = __expf(mr[i] - mnew);
      lr[i] = lr[i] * corr + rs;
      mr[i] = mnew;
#pragma unroll
      for (int c = 0; c < 8; ++c) O[i][c] *= corr;
      const int r = rg * 4 + i;
      float2 pv = {p0, p1};
      *(float2*)&Pw[wv][r][swzp(r, cg * 2)] = pv;
    }
#pragma unroll
    for (int k0 = 0; k0 < 16; k0 += 4) {
      float4 pa[4];
#pragma unroll
      for (int i = 0; i < 4; ++i) {
        const int r = rg * 4 + i;
        pa[i] = *(const float4*)&Pw[wv][r][swzp(r, k0)];
      }
#pragma unroll
      for (int jj = 0; jj < 4; ++jj) {
        const int vr = k0 + jj;
        const float4 v0 = *(const float4*)&Vs[cur][vr][swz(vr, cg * 8)];
        const float4 v1 = *(const float4*)&Vs[cur][vr][swz(vr, cg * 8 + 4)];
#pragma unroll
        for (int i = 0; i < 4; ++i) {
          const float p = (jj == 0) ? pa[i].x
                          : (jj == 1) ? pa[i].y
                          : (jj == 2) ? pa[i].z : pa[i].w;
          O[i][0] = fmaf(p, v0.x, O[i][0]);
          O[i][1] = fmaf(p, v0.y, O[i][1]);
          O[i][2] = fmaf(p, v0.z, O[i][2]);
          O[i][3] = fmaf(p, v0.w, O[i][3]);
          O[i][4] = fmaf(p, v1.x, O[i][4]);
          O[i][5] = fmaf(p, v1.y, O[i][5]);
          O[i][6] = fmaf(p, v1.z, O[i][6]);
          O[i][7] = fmaf(p, v1.w, O[i][7]);
        }
      }
    }
    __syncthreads();
  }
#pragma unroll
  for (int i = 0; i < 4; ++i) {
    const float inv = 1.0f / lr[i];
    float* orow =
        ctx + ((size_t)(b * Ss + q0 + rg * 4 + i)) * Dd + h * HDim + cg * 8;
    float4 o0 = {O[i][0] * inv, O[i][1] * inv, O[i][2] * inv, O[i][3] * inv};
    float4 o1 = {O[i][4] * inv, O[i][5] * inv, O[i][6] * inv, O[i][7] * inv};
    *(float4*)(orow) = o0;
    *(float4*)(orow + 4) = o1;
  }
#undef STAGE_KV
}

// ---------------------------------------------------------------------------
// Router: bitonic full-sort of packed u64 keys (exact stable top-k).
// Pooled max over 4 mtiles/batch (aff GEMM tile is 256 rows).
// ---------------------------------------------------------------------------
__device__ inline unsigned int f2s(float f) {
  unsigned int u = __float_as_uint(f);
  return (u >> 31) ? ~u : (u | 0x80000000u);
}
__device__ inline float s2f(unsigned int s) {
  unsigned int u = (s >> 31) ? (s & 0x7fffffffu) : ~s;
  return __uint_as_float(u);
}

__global__ __launch_bounds__(256) void router_kernel(
    const float* __restrict__ partial, const float* __restrict__ aff_b,
    const int* __restrict__ kp, float* __restrict__ out, int out_size) {
  __shared__ unsigned long long keys[Nn];  // 32 KB
  __shared__ float lorig[Nn];              // 16 KB
  __shared__ float rv[4];
  const int tid = threadIdx.x;
  const int b = blockIdx.x;
  const int kcount = *kp;
  float* idx_out = out;
  float* w_out = out + (out_size - Mm * Dd - Bb * Nn);
  for (int n = tid; n < Nn; n += 256) {
    float m = partial[(size_t)(b * 4) * Nn + n];
#pragma unroll
    for (int t = 1; t < 4; ++t)
      m = fmaxf(m, partial[(size_t)(b * 4 + t) * Nn + n]);
    float lg = (m + aff_b[n]) * 0.5f;  // /TEMPERATURE
    lorig[n] = lg;
    keys[n] = ((unsigned long long)f2s(lg) << 32) | (unsigned int)(Nn - 1 - n);
  }
  __syncthreads();
  for (int kk = 2; kk <= Nn; kk <<= 1) {
    for (int j = kk >> 1; j > 0; j >>= 1) {
#pragma unroll 4
      for (int t = tid; t < Nn / 2; t += 256) {
        const int i = 2 * j * (t / j) + (t % j);
        const int p = i + j;
        const bool desc = ((i & kk) == 0);
        unsigned long long a = keys[i], c = keys[p];
        if (desc ? (a < c) : (a > c)) { keys[i] = c; keys[p] = a; }
      }
      __syncthreads();
    }
  }
  const float gm = s2f((unsigned int)(keys[0] >> 32));
  float se = 0.f;
  for (int n = tid; n < Nn; n += 256) se += expf(lorig[n] - gm);
#pragma unroll
  for (int msk = 1; msk < 64; msk <<= 1) se += __shfl_xor(se, msk);
  if ((tid & 63) == 0) rv[tid >> 6] = se;
  __syncthreads();
  se = rv[0] + rv[1] + rv[2] + rv[3];
  __syncthreads();
  float es = 0.f;
  for (int p = tid; p < kcount; p += 256)
    es += expf(s2f((unsigned int)(keys[p] >> 32)) - gm);
#pragma unroll
  for (int msk = 1; msk < 64; msk <<= 1) es += __shfl_xor(es, msk);
  if ((tid & 63) == 0) rv[tid >> 6] = es;
  __syncthreads();
  es = rv[0] + rv[1] + rv[2] + rv[3];
  const float wd = es / se + 1e-8f;
  for (int n = tid; n < Nn; n += 256) w_out[(size_t)b * Nn + n] = 0.f;
  __syncthreads();
  for (int p = tid; p < kcount; p += 256) {
    const unsigned long long kkey2 = keys[p];
    const int n = Nn - 1 - (int)(kkey2 & 0xffffffffu);
    const float val = s2f((unsigned int)(kkey2 >> 32));
    idx_out[b * kcount + p] = (float)n;
    w_out[(size_t)b * Nn + n] = (expf(val - gm) / se) / wd;
  }
}

}  // namespace

extern "C" void kernel_launch(void* const* d_in, const int* in_sizes, int n_in,
                              void* d_out, int out_size, void* d_ws,
                              size_t ws_size, hipStream_t stream) {
  (void)in_sizes; (void)n_in; (void)ws_size;
  const float* x = (const float*)d_in[0];
  const float* in_proj_w = (const float*)d_in[1];
  const float* in_proj_b = (const float*)d_in[2];
  const float* out_w = (const float*)d_in[3];
  const float* out_b = (const float*)d_in[4];
  const float* aff_w = (const float*)d_in[5];
  const float* aff_b = (const float*)d_in[6];
  const int* kp = (const int*)d_in[7];

  float* qkv = (float*)d_ws;                 // [4096, 3072] = 50.3 MB
  float* ctxws = qkv + (size_t)Mm * 3 * Dd;  // [4096, 1024] = 16.8 MB
  float* partial = ctxws + (size_t)Mm * Dd;  // [16, 4096]   = 0.25 MB

  float* out = (float*)d_out;
  float* ctx_out = out + ((size_t)out_size - (size_t)Mm * Dd);  // context tail

  // 1) qkv = x @ in_proj_w^T + b  (TM=8, BM=128: 24x32 = 768 balanced blocks)
  gemm_f32<0, 8><<<dim3(3 * Dd / 128, Mm / 128), 256, 0, stream>>>(
      x, in_proj_w, in_proj_b, qkv, Dd, 3 * Dd);
  // 2) attention -> ctxws  (512 four-wave blocks, XCD-local)
  attn_kernel<<<dim3(Ss / 128 * Bb * Hh), 256, 0, stream>>>(qkv, ctxws);
  // 3) context = ctxws @ out_w^T + b  (TM=4, BM=64 -> 512 blocks)
  gemm_f32<0, 4><<<dim3(Dd / 128, Mm / 64), 256, 0, stream>>>(
      ctxws, out_w, out_b, ctx_out, Dd, Dd);
  // 4) partial[mtile][n] = max over 256 rows  (TM=16: 32x16 = 512 blocks)
  gemm_f32<2, 16><<<dim3(Nn / 128, Mm / 256), 256, 0, stream>>>(
      ctx_out, aff_w, nullptr, partial, Dd, Nn);
  // 5) router: pooled max (4 tiles), softmax, exact top-k, weights
  router_kernel<<<dim3(Bb), 256, 0, stream>>>(partial, aff_b, kp, out, out_size);
}

// Round 14
// 1224.366 us; speedup vs baseline: 1.1419x; 1.0185x over previous
//
#include <hip/hip_runtime.h>
#include <math.h>

namespace {

constexpr int Bb = 4, Ss = 1024, Dd = 1024, Hh = 16, HDim = 64, Nn = 4096;
constexpr int Mm = Bb * Ss; // 4096

__device__ inline void gload_lds16(const void* g, void* l) {
  __builtin_amdgcn_global_load_lds(
      (const __attribute__((address_space(1))) void*)g,
      (__attribute__((address_space(3))) void*)l, 16, 0, 0);
}

// ---------------------------------------------------------------------------
// fp32 GEMM v9 (r13-validated): C[M,N] = A[M,K] @ W[N,K]^T (+ bias[N]).
// 256 threads = 4 waves (2x2 quadrants of BM/2 x 64).
// TM=16 (BM=256, BK=8): aff GEMM, 512 blocks. TM=8 (BM=128, BK=16): qkv,
// 768 balanced blocks. TM=4 (BM=64, BK=16): ctx, 512 blocks.
// Double-buffered LDS, ONE barrier/tile, prefetch after barrier.
// MODE 0: C = acc + bias.  MODE 2 (TM=16): partial[blockIdx.y][n] = max
// over the tile's 256 rows (router pooled max; 4 tiles/batch).
// ---------------------------------------------------------------------------
template <int MODE, int TM>
__global__ __launch_bounds__(256, 2) void gemm_f32(
    const float* __restrict__ A, const float* __restrict__ W,
    const float* __restrict__ bias, float* __restrict__ C, const int K,
    const int ldc) {
  constexpr int BM = TM * 16;
  constexpr int BK = (TM == 16) ? 8 : 16;
  __shared__ float As[2][BK][BM];
  __shared__ float Ws[2][BK][128];
  __shared__ float red[2][128];
  const int tid = threadIdx.x;
  const int lane = tid & 63, wv = tid >> 6;
  const int wm = wv >> 1, wn = wv & 1;
  const int lty = lane >> 3, ltx = lane & 7;
  const int m0 = blockIdx.y * BM, n0 = blockIdx.x * 128;
  const int row0 = wm * (BM / 2) + lty * ((TM == 16) ? 8 : TM);
  const int col0 = wn * 64 + ltx * 8;
  const int asrow = (TM == 16) ? tid : ((TM == 8) ? (tid >> 1) : (tid >> 2));
  const int asoff = (TM == 16) ? 0
                    : ((TM == 8) ? ((tid & 1) * 8) : ((tid & 3) * 4));
  const int bsrow = tid >> 1;
  const int bsoff = (TM == 16) ? ((tid & 1) * 4) : ((tid & 1) * 8);
  const float* Ap = A + (size_t)(m0 + asrow) * K + asoff;
  const float* Wp = W + (size_t)(n0 + bsrow) * K + bsoff;

  float4 ar[2], w0r, w1r;
  ar[0] = *(const float4*)(Ap);
  if constexpr (TM >= 8) ar[1] = *(const float4*)(Ap + 4);
  w0r = *(const float4*)(Wp);
  if constexpr (TM != 16) w1r = *(const float4*)(Wp + 4);

  float acc[TM][8] = {};
  const int NT = K / BK;
#pragma unroll 1
  for (int kt = 0; kt < NT; ++kt) {
    float* Ab = &As[kt & 1][0][0];
    float* Wb = &Ws[kt & 1][0][0];
    if constexpr (TM == 16) {
#pragma unroll
      for (int c = 0; c < 8; ++c) Ab[c * BM + asrow] = ((const float*)ar)[c];
      Wb[(bsoff + 0) * 128 + bsrow] = w0r.x;
      Wb[(bsoff + 1) * 128 + bsrow] = w0r.y;
      Wb[(bsoff + 2) * 128 + bsrow] = w0r.z;
      Wb[(bsoff + 3) * 128 + bsrow] = w0r.w;
    } else if constexpr (TM == 8) {
#pragma unroll
      for (int c = 0; c < 8; ++c)
        Ab[(asoff + c) * BM + asrow] = ((const float*)ar)[c];
      Wb[(bsoff + 0) * 128 + bsrow] = w0r.x;
      Wb[(bsoff + 1) * 128 + bsrow] = w0r.y;
      Wb[(bsoff + 2) * 128 + bsrow] = w0r.z;
      Wb[(bsoff + 3) * 128 + bsrow] = w0r.w;
      Wb[(bsoff + 4) * 128 + bsrow] = w1r.x;
      Wb[(bsoff + 5) * 128 + bsrow] = w1r.y;
      Wb[(bsoff + 6) * 128 + bsrow] = w1r.z;
      Wb[(bsoff + 7) * 128 + bsrow] = w1r.w;
    } else {
      Ab[(asoff + 0) * BM + asrow] = ar[0].x;
      Ab[(asoff + 1) * BM + asrow] = ar[0].y;
      Ab[(asoff + 2) * BM + asrow] = ar[0].z;
      Ab[(asoff + 3) * BM + asrow] = ar[0].w;
      Wb[(bsoff + 0) * 128 + bsrow] = w0r.x;
      Wb[(bsoff + 1) * 128 + bsrow] = w0r.y;
      Wb[(bsoff + 2) * 128 + bsrow] = w0r.z;
      Wb[(bsoff + 3) * 128 + bsrow] = w0r.w;
      Wb[(bsoff + 4) * 128 + bsrow] = w1r.x;
      Wb[(bsoff + 5) * 128 + bsrow] = w1r.y;
      Wb[(bsoff + 6) * 128 + bsrow] = w1r.z;
      Wb[(bsoff + 7) * 128 + bsrow] = w1r.w;
    }
    __syncthreads();  // tile visible; single barrier per iteration
    if (kt + 1 < NT) {
      const int kb = (kt + 1) * BK;
      ar[0] = *(const float4*)(Ap + kb);
      if constexpr (TM >= 8) ar[1] = *(const float4*)(Ap + kb + 4);
      w0r = *(const float4*)(Wp + kb);
      if constexpr (TM != 16) w1r = *(const float4*)(Wp + kb + 4);
    }
#pragma unroll
    for (int kk = 0; kk < BK; ++kk) {
      float av[TM];
      {
        float4 aq0 = *(const float4*)&Ab[kk * BM + row0];
        av[0] = aq0.x; av[1] = aq0.y; av[2] = aq0.z; av[3] = aq0.w;
      }
      if constexpr (TM >= 8) {
        float4 aq1 = *(const float4*)&Ab[kk * BM + row0 + 4];
        av[4] = aq1.x; av[5] = aq1.y; av[6] = aq1.z; av[7] = aq1.w;
      }
      if constexpr (TM == 16) {
        float4 aq2 = *(const float4*)&Ab[kk * BM + row0 + 64];
        float4 aq3 = *(const float4*)&Ab[kk * BM + row0 + 68];
        av[8] = aq2.x; av[9] = aq2.y; av[10] = aq2.z; av[11] = aq2.w;
        av[12] = aq3.x; av[13] = aq3.y; av[14] = aq3.z; av[15] = aq3.w;
      }
      float4 bq0 = *(const float4*)&Wb[kk * 128 + col0];
      float4 bq1 = *(const float4*)&Wb[kk * 128 + col0 + 4];
      const float bv[8] = {bq0.x, bq0.y, bq0.z, bq0.w,
                           bq1.x, bq1.y, bq1.z, bq1.w};
#pragma unroll
      for (int i = 0; i < TM; ++i)
#pragma unroll
        for (int j = 0; j < 8; ++j)
          acc[i][j] = fmaf(av[i], bv[j], acc[i][j]);
    }
  }

  if constexpr (MODE == 0) {
    float4 bb0 = *(const float4*)&bias[n0 + col0];
    float4 bb1 = *(const float4*)&bias[n0 + col0 + 4];
    const float bvv[8] = {bb0.x, bb0.y, bb0.z, bb0.w,
                          bb1.x, bb1.y, bb1.z, bb1.w};
#pragma unroll
    for (int i = 0; i < TM; ++i) {
      const int roff = (TM == 16) ? ((i & 7) + (i >> 3) * 64) : i;
      float* crow = C + (size_t)(m0 + row0 + roff) * ldc + n0 + col0;
      float4 o0 = {acc[i][0] + bvv[0], acc[i][1] + bvv[1],
                   acc[i][2] + bvv[2], acc[i][3] + bvv[3]};
      float4 o1 = {acc[i][4] + bvv[4], acc[i][5] + bvv[5],
                   acc[i][6] + bvv[6], acc[i][7] + bvv[7]};
      *(float4*)(crow) = o0;
      *(float4*)(crow + 4) = o1;
    }
  } else {
    float cm[8];
#pragma unroll
    for (int j = 0; j < 8; ++j) {
      float m = acc[0][j];
#pragma unroll
      for (int i = 1; i < TM; ++i) m = fmaxf(m, acc[i][j]);
      m = fmaxf(m, __shfl_xor(m, 8));
      m = fmaxf(m, __shfl_xor(m, 16));
      m = fmaxf(m, __shfl_xor(m, 32));
      cm[j] = m;
    }
    __syncthreads();
    if (lty == 0) {
      float4 c0 = {cm[0], cm[1], cm[2], cm[3]};
      float4 c1 = {cm[4], cm[5], cm[6], cm[7]};
      *(float4*)&red[wm][wn * 64 + ltx * 8] = c0;
      *(float4*)&red[wm][wn * 64 + ltx * 8 + 4] = c1;
    }
    __syncthreads();
    if (tid < 128)
      C[(size_t)blockIdx.y * ldc + n0 + tid] =
          fmaxf(red[0][tid], red[1][tid]);
  }
}

// ---------------------------------------------------------------------------
// Flash attention v7: v6 structure (4-wave blocks, shared K/V via
// global_load_lds, XCD-local grid) with KVBLK 16->32 and sc[4][4] micro:
// QK b128 reads drop 192->128 per 32 k-rows (kv[4] amortizes qa[4] over 2x
// FMAs); barriers halved (32 total). LDS = Qs 32K + K/V dbuf 32K + P 16K =
// 80 KB -> DYNAMIC extern __shared__ (>64K static limit; m201 example runs
// 128 KiB on gfx950) -> still 2 blocks/CU = 8 waves.
// Swizzle: granule-XOR swz(r,c) = c ^ (kkey(r)<<2); K-row keys for rows
// cg*4+j are {0,4,1,5,2,6,3,7} -> distinct -> conflict-free; every "+4"
// kept INSIDE swz() (outside would mis-map when key is odd).
// ---------------------------------------------------------------------------
__device__ __forceinline__ int kkey(int r) { return ((r >> 3) ^ r) & 7; }
__device__ __forceinline__ int swz(int r, int c) { return c ^ (kkey(r) << 2); }

__global__ __launch_bounds__(256, 2) void attn_kernel(
    const float* __restrict__ qkv, float* __restrict__ ctx) {
  extern __shared__ float sm[];
  float* Qs = sm;            // [4][32][64]  32 KB  wv*2048 + r*64 + c
  float* Ks = sm + 8192;     // [2][32][64]  16 KB  bf*2048 + r*64 + c
  float* Vs = sm + 12288;    // [2][32][64]  16 KB
  float* Pw = sm + 16384;    // [4][32][32]  16 KB  wv*1024 + r*32 + c
  const int tid = threadIdx.x, wv = tid >> 6, lane = tid & 63;
  const int rg = lane >> 3, cg = lane & 7;
  const int id = blockIdx.x;
  const int qb = id >> 6, bh = id & 63;  // bh = id mod 64 -> XCD-local heads
  const int b = bh >> 4, h = bh & 15;
  const int q0 = qb * 128 + wv * 32;
  const size_t rstride = 3 * Dd;
  const float* qbp = qkv + (size_t)b * Ss * rstride + h * HDim;
  const float* kbp = qbp + Dd;
  const float* vbp = qbp + 2 * Dd;

  // stage this wave's Q tile (lane -> row lane>>1, half (lane&1)*32)
  {
    const int r = lane >> 1, ch = (lane & 1) * 32;
    const float* qr = qbp + (size_t)(q0 + r) * rstride + ch;
#pragma unroll
    for (int c = 0; c < 32; c += 4)
      Qs[wv * 2048 + r * 64 + swz(r, ch + c)] = 0.f,  // placeholder overwritten
      *(float4*)&Qs[wv * 2048 + r * 64 + swz(r, ch + c)] =
          *(const float4*)(qr + c);
  }

  // K/V staging: 16 gloads per 32-row tile (K:8, V:8), 4 per wave.
  // gload g covers 4 rows: lane l -> row rb*4 + (l>>4), col (l&15)*4;
  // source col pre-swizzled so LDS granule g holds logical granule g^key.
  const int srow = lane >> 4;
  const int scol = (lane & 15) * 4;
#define STAGE_KV(KT, BF)                                                      \
  {                                                                           \
    _Pragma("unroll") for (int j = 0; j < 4; ++j) {                           \
      const int g = wv * 4 + j;                                               \
      const int rb = g & 7;                                                   \
      const int rr = rb * 4 + srow;                                           \
      const int cc = swz(rr, scol);                                           \
      if (g < 8)                                                              \
        gload_lds16(kbp + (size_t)((KT) + rr) * rstride + cc,                 \
                    Ks + (BF)*2048 + rb * 256);                               \
      else                                                                    \
        gload_lds16(vbp + (size_t)((KT) + rr) * rstride + cc,                 \
                    Vs + (BF)*2048 + rb * 256);                               \
    }                                                                         \
  }

  STAGE_KV(0, 0);
  __syncthreads();  // prologue: tile 0 visible (drains vmcnt), Q staged

  float O[4][8] = {};
  float mr[4], lr[4];
#pragma unroll
  for (int i = 0; i < 4; ++i) { mr[i] = -INFINITY; lr[i] = 0.f; }

#pragma unroll 1
  for (int t = 0; t < Ss / 32; ++t) {
    const int cur = t & 1;
    if (t + 1 < Ss / 32) STAGE_KV((t + 1) * 32, cur ^ 1);  // into buf^1
    // ---- QK^T: sc[i][j] = sum_d Q[rg*4+i][d] * K[cg*4+j][d]
    float sc[4][4] = {};
#pragma unroll
    for (int d0 = 0; d0 < HDim; d0 += 4) {
      float4 qa[4], kv[4];
#pragma unroll
      for (int i = 0; i < 4; ++i) {
        const int r = rg * 4 + i;
        qa[i] = *(const float4*)&Qs[wv * 2048 + r * 64 + swz(r, d0)];
      }
#pragma unroll
      for (int j = 0; j < 4; ++j) {
        const int r = cg * 4 + j;
        kv[j] = *(const float4*)&Ks[cur * 2048 + r * 64 + swz(r, d0)];
      }
#pragma unroll
      for (int i = 0; i < 4; ++i)
#pragma unroll
        for (int j = 0; j < 4; ++j) {
          sc[i][j] = fmaf(qa[i].x, kv[j].x, sc[i][j]);
          sc[i][j] = fmaf(qa[i].y, kv[j].y, sc[i][j]);
          sc[i][j] = fmaf(qa[i].z, kv[j].z, sc[i][j]);
          sc[i][j] = fmaf(qa[i].w, kv[j].w, sc[i][j]);
        }
    }
    // ---- online softmax (rows rg*4+i; 4 cols/lane; reduce over cg lanes)
#pragma unroll
    for (int i = 0; i < 4; ++i) {
      float sv[4];
#pragma unroll
      for (int j = 0; j < 4; ++j) sv[j] = sc[i][j] * 0.125f;
      float tm = fmaxf(fmaxf(sv[0], sv[1]), fmaxf(sv[2], sv[3]));
      tm = fmaxf(tm, __shfl_xor(tm, 1));
      tm = fmaxf(tm, __shfl_xor(tm, 2));
      tm = fmaxf(tm, __shfl_xor(tm, 4));
      const float mnew = fmaxf(mr[i], tm);
      float p[4];
      float rs = 0.f;
#pragma unroll
      for (int j = 0; j < 4; ++j) { p[j] = __expf(sv[j] - mnew); rs += p[j]; }
      rs += __shfl_xor(rs, 1);
      rs += __shfl_xor(rs, 2);
      rs += __shfl_xor(rs, 4);
      const float corr = __expf(mr[i] - mnew);
      lr[i] = lr[i] * corr + rs;
      mr[i] = mnew;
#pragma unroll
      for (int c = 0; c < 8; ++c) O[i][c] *= corr;
      const int r = rg * 4 + i;
      float4 pv = {p[0], p[1], p[2], p[3]};
      *(float4*)&Pw[wv * 1024 + r * 32 + swz(r, cg * 4)] = pv;  // wave-private
    }
    // ---- PV: O[i][c] += sum_k P[r][k] * V[k][cg*8+c]
#pragma unroll
    for (int k0 = 0; k0 < 32; k0 += 4) {
      float4 pa[4];
#pragma unroll
      for (int i = 0; i < 4; ++i) {
        const int r = rg * 4 + i;
        pa[i] = *(const float4*)&Pw[wv * 1024 + r * 32 + swz(r, k0)];
      }
#pragma unroll
      for (int jj = 0; jj < 4; ++jj) {
        const int vr = k0 + jj;
        const float4 v0 =
            *(const float4*)&Vs[cur * 2048 + vr * 64 + swz(vr, cg * 8)];
        const float4 v1 =
            *(const float4*)&Vs[cur * 2048 + vr * 64 + swz(vr, cg * 8 + 4)];
#pragma unroll
        for (int i = 0; i < 4; ++i) {
          const float p = (jj == 0) ? pa[i].x
                          : (jj == 1) ? pa[i].y
                          : (jj == 2) ? pa[i].z : pa[i].w;
          O[i][0] = fmaf(p, v0.x, O[i][0]);
          O[i][1] = fmaf(p, v0.y, O[i][1]);
          O[i][2] = fmaf(p, v0.z, O[i][2]);
          O[i][3] = fmaf(p, v0.w, O[i][3]);
          O[i][4] = fmaf(p, v1.x, O[i][4]);
          O[i][5] = fmaf(p, v1.y, O[i][5]);
          O[i][6] = fmaf(p, v1.z, O[i][6]);
          O[i][7] = fmaf(p, v1.w, O[i][7]);
        }
      }
    }
    // ONE barrier: drains this wave's gloads (issued at loop top, hidden
    // under the compute) and retires all reads of buf[cur] before its
    // overwrite at t+2.
    __syncthreads();
  }
#pragma unroll
  for (int i = 0; i < 4; ++i) {
    const float inv = 1.0f / lr[i];
    float* orow =
        ctx + ((size_t)(b * Ss + q0 + rg * 4 + i)) * Dd + h * HDim + cg * 8;
    float4 o0 = {O[i][0] * inv, O[i][1] * inv, O[i][2] * inv, O[i][3] * inv};
    float4 o1 = {O[i][4] * inv, O[i][5] * inv, O[i][6] * inv, O[i][7] * inv};
    *(float4*)(orow) = o0;
    *(float4*)(orow + 4) = o1;
  }
#undef STAGE_KV
}

// ---------------------------------------------------------------------------
// Router: bitonic full-sort of packed u64 keys (exact stable top-k).
// Pooled max over 4 mtiles/batch (aff GEMM tile is 256 rows).
// ---------------------------------------------------------------------------
__device__ inline unsigned int f2s(float f) {
  unsigned int u = __float_as_uint(f);
  return (u >> 31) ? ~u : (u | 0x80000000u);
}
__device__ inline float s2f(unsigned int s) {
  unsigned int u = (s >> 31) ? (s & 0x7fffffffu) : ~s;
  return __uint_as_float(u);
}

__global__ __launch_bounds__(256) void router_kernel(
    const float* __restrict__ partial, const float* __restrict__ aff_b,
    const int* __restrict__ kp, float* __restrict__ out, int out_size) {
  __shared__ unsigned long long keys[Nn];  // 32 KB
  __shared__ float lorig[Nn];              // 16 KB
  __shared__ float rv[4];
  const int tid = threadIdx.x;
  const int b = blockIdx.x;
  const int kcount = *kp;
  float* idx_out = out;
  float* w_out = out + (out_size - Mm * Dd - Bb * Nn);
  for (int n = tid; n < Nn; n += 256) {
    float m = partial[(size_t)(b * 4) * Nn + n];
#pragma unroll
    for (int t = 1; t < 4; ++t)
      m = fmaxf(m, partial[(size_t)(b * 4 + t) * Nn + n]);
    float lg = (m + aff_b[n]) * 0.5f;  // /TEMPERATURE
    lorig[n] = lg;
    keys[n] = ((unsigned long long)f2s(lg) << 32) | (unsigned int)(Nn - 1 - n);
  }
  __syncthreads();
  for (int kk = 2; kk <= Nn; kk <<= 1) {
    for (int j = kk >> 1; j > 0; j >>= 1) {
#pragma unroll 4
      for (int t = tid; t < Nn / 2; t += 256) {
        const int i = 2 * j * (t / j) + (t % j);
        const int p = i + j;
        const bool desc = ((i & kk) == 0);
        unsigned long long a = keys[i], c = keys[p];
        if (desc ? (a < c) : (a > c)) { keys[i] = c; keys[p] = a; }
      }
      __syncthreads();
    }
  }
  const float gm = s2f((unsigned int)(keys[0] >> 32));
  float se = 0.f;
  for (int n = tid; n < Nn; n += 256) se += expf(lorig[n] - gm);
#pragma unroll
  for (int msk = 1; msk < 64; msk <<= 1) se += __shfl_xor(se, msk);
  if ((tid & 63) == 0) rv[tid >> 6] = se;
  __syncthreads();
  se = rv[0] + rv[1] + rv[2] + rv[3];
  __syncthreads();
  float es = 0.f;
  for (int p = tid; p < kcount; p += 256)
    es += expf(s2f((unsigned int)(keys[p] >> 32)) - gm);
#pragma unroll
  for (int msk = 1; msk < 64; msk <<= 1) es += __shfl_xor(es, msk);
  if ((tid & 63) == 0) rv[tid >> 6] = es;
  __syncthreads();
  es = rv[0] + rv[1] + rv[2] + rv[3];
  const float wd = es / se + 1e-8f;
  for (int n = tid; n < Nn; n += 256) w_out[(size_t)b * Nn + n] = 0.f;
  __syncthreads();
  for (int p = tid; p < kcount; p += 256) {
    const unsigned long long kkey2 = keys[p];
    const int n = Nn - 1 - (int)(kkey2 & 0xffffffffu);
    const float val = s2f((unsigned int)(kkey2 >> 32));
    idx_out[b * kcount + p] = (float)n;
    w_out[(size_t)b * Nn + n] = (expf(val - gm) / se) / wd;
  }
}

}  // namespace

extern "C" void kernel_launch(void* const* d_in, const int* in_sizes, int n_in,
                              void* d_out, int out_size, void* d_ws,
                              size_t ws_size, hipStream_t stream) {
  (void)in_sizes; (void)n_in; (void)ws_size;
  const float* x = (const float*)d_in[0];
  const float* in_proj_w = (const float*)d_in[1];
  const float* in_proj_b = (const float*)d_in[2];
  const float* out_w = (const float*)d_in[3];
  const float* out_b = (const float*)d_in[4];
  const float* aff_w = (const float*)d_in[5];
  const float* aff_b = (const float*)d_in[6];
  const int* kp = (const int*)d_in[7];

  float* qkv = (float*)d_ws;                 // [4096, 3072] = 50.3 MB
  float* ctxws = qkv + (size_t)Mm * 3 * Dd;  // [4096, 1024] = 16.8 MB
  float* partial = ctxws + (size_t)Mm * Dd;  // [16, 4096]   = 0.25 MB

  float* out = (float*)d_out;
  float* ctx_out = out + ((size_t)out_size - (size_t)Mm * Dd);  // context tail

  // 1) qkv = x @ in_proj_w^T + b  (TM=8, BM=128: 24x32 = 768 balanced blocks)
  gemm_f32<0, 8><<<dim3(3 * Dd / 128, Mm / 128), 256, 0, stream>>>(
      x, in_proj_w, in_proj_b, qkv, Dd, 3 * Dd);
  // 2) attention -> ctxws  (512 blocks, 80 KB dynamic LDS, XCD-local)
  attn_kernel<<<dim3(Ss / 128 * Bb * Hh), 256, 81920, stream>>>(qkv, ctxws);
  // 3) context = ctxws @ out_w^T + b  (TM=4, BM=64 -> 512 blocks)
  gemm_f32<0, 4><<<dim3(Dd / 128, Mm / 64), 256, 0, stream>>>(
      ctxws, out_w, out_b, ctx_out, Dd, Dd);
  // 4) partial[mtile][n] = max over 256 rows  (TM=16: 32x16 = 512 blocks)
  gemm_f32<2, 16><<<dim3(Nn / 128, Mm / 256), 256, 0, stream>>>(
      ctx_out, aff_w, nullptr, partial, Dd, Nn);
  // 5) router: pooled max (4 tiles), softmax, exact top-k, weights
  router_kernel<<<dim3(Bb), 256, 0, stream>>>(partial, aff_b, kp, out, out_size);
}